// Round 1
// baseline (1435.727 us; speedup 1.0000x reference)
//
#include <hip/hip_runtime.h>
#include <hip/hip_bf16.h>
#include <cstdint>

typedef __attribute__((ext_vector_type(8))) short short8;
typedef __attribute__((ext_vector_type(4))) float floatx4;

#define HIDDEN 128
#define NOUT 256

// ---------------------------------------------------------------------------
// Kernel 1: one-time weight convert + transpose to bf16.
// WdT[n][k] = W_down[k][n]   (256 x 128)
// WsT[l][n][k] = Ws[l][k][n] (3 x 256 x 256)
// Transposed layout makes the MFMA B-fragment reads contiguous (ds_read_b128).
// ---------------------------------------------------------------------------
__global__ __launch_bounds__(256) void prep_weights(
    const float* __restrict__ Wd, const float* __restrict__ Ws,
    __hip_bfloat16* __restrict__ WdT, __hip_bfloat16* __restrict__ WsT)
{
    int tid = blockIdx.x * 256 + threadIdx.x;
    if (tid < 256 * 128) {
        int n = tid >> 7, k = tid & 127;
        WdT[tid] = __float2bfloat16(Wd[k * 256 + n]);
    }
    int tid2 = tid - 256 * 128;
    if (tid2 >= 0 && tid2 < 3 * 256 * 256) {
        int l = tid2 >> 16;
        int rem = tid2 & 65535;
        int n = rem >> 8, k = rem & 255;
        WsT[tid2] = __float2bfloat16(Ws[l * 65536 + k * 256 + n]);
    }
}

// ---------------------------------------------------------------------------
// Kernel 2: gate + scatter-add.  g = (rbf @ W_rbf) * x; hacc[i[e]] += g.
// Block = 256 threads = 8 edges x 32 threads; each thread does 4 hidden ch.
// All fp32 (exact); 4 atomicAdds per thread -> accumulator lives in L2/L3.
// ---------------------------------------------------------------------------
__global__ __launch_bounds__(256) void gate_scatter(
    const float* __restrict__ x, const float* __restrict__ rbf,
    const int* __restrict__ idx, const float* __restrict__ Wrbf,
    float* __restrict__ hacc, int E)
{
    __shared__ float wr[6 * HIDDEN];
    __shared__ float rbf_s[48];
    __shared__ int idx_s[8];
    int t = threadIdx.x;
    for (int q = t; q < 6 * HIDDEN; q += 256) wr[q] = Wrbf[q];
    long e0 = (long)blockIdx.x * 8;
    if (t < 48) {
        long j = e0 * 6 + t;
        rbf_s[t] = (j < (long)E * 6) ? rbf[j] : 0.f;
    }
    if (t < 8) {
        long e = e0 + t;
        idx_s[t] = (e < E) ? idx[e] : 0;
    }
    __syncthreads();

    int le = t >> 5;      // edge within block (0..7)
    int j  = t & 31;      // hidden chunk (0..31), 4 floats each
    long e = e0 + le;
    if (e >= E) return;
    int h0 = j * 4;

    float c0 = 0.f, c1 = 0.f, c2 = 0.f, c3 = 0.f;
#pragma unroll
    for (int r = 0; r < 6; ++r) {
        float rv = rbf_s[le * 6 + r];
        const float* w = &wr[r * HIDDEN + h0];
        c0 += rv * w[0]; c1 += rv * w[1]; c2 += rv * w[2]; c3 += rv * w[3];
    }
    const float4 xv = *(const float4*)&x[e * HIDDEN + h0];
    float* dst = &hacc[(long)idx_s[le] * HIDDEN + h0];
    atomicAdd(dst + 0, c0 * xv.x);
    atomicAdd(dst + 1, c1 * xv.y);
    atomicAdd(dst + 2, c2 * xv.z);
    atomicAdd(dst + 3, c3 * xv.w);
}

// ---------------------------------------------------------------------------
// Kernel 3: bf16 MFMA GEMM  C[M][256] = act(A[M][K] @ B[K][256] + bias)
// B passed pre-transposed (BT[n][k], bf16).  Block tile 64(M) x 256(N),
// BK=64, 4 waves: wave w owns columns [64w, 64w+64).  16x16x32 bf16 MFMA.
// Verified layouts: A[m=lane&15][k=(lane>>4)*8+j]; B-frag same with n=lane&15;
// C/D: col=lane&15, row=(lane>>4)*4+reg.
// ---------------------------------------------------------------------------
template <int K, bool A_F32, bool BIAS, bool SILU, bool OUT_F32>
__global__ __launch_bounds__(256) void gemm_k(
    const void* __restrict__ Ap, const __hip_bfloat16* __restrict__ BT,
    const float* __restrict__ bias, void* __restrict__ Cp, int M)
{
    __shared__ __hip_bfloat16 Al[64][72];    // +8 pad: breaks pow2 bank stride
    __shared__ __hip_bfloat16 Bl[256][72];

    int t = threadIdx.x;
    int lane = t & 63, w = t >> 6;
    int q = lane >> 4, r16 = lane & 15;
    int m0 = blockIdx.x * 64;

    floatx4 acc[4][4] = {};

    for (int k0 = 0; k0 < K; k0 += 64) {
        // ---- stage A tile (64 x 64) ----
        if (A_F32) {
            const float* A = (const float*)Ap;
#pragma unroll
            for (int it = 0; it < 4; ++it) {
                int idx = it * 256 + t;          // 0..1023 float4 chunks
                int row = idx >> 4;
                int col = (idx & 15) * 4;
                int gr = m0 + row; if (gr >= M) gr = M - 1;
                float4 v = *(const float4*)&A[(long)gr * K + k0 + col];
                Al[row][col + 0] = __float2bfloat16(v.x);
                Al[row][col + 1] = __float2bfloat16(v.y);
                Al[row][col + 2] = __float2bfloat16(v.z);
                Al[row][col + 3] = __float2bfloat16(v.w);
            }
        } else {
            const __hip_bfloat16* A = (const __hip_bfloat16*)Ap;
#pragma unroll
            for (int it = 0; it < 2; ++it) {
                int idx = it * 256 + t;          // 0..511 16B chunks
                int row = idx >> 3;
                int col = (idx & 7) * 8;
                int gr = m0 + row; if (gr >= M) gr = M - 1;
                uint4 v = *(const uint4*)&A[(long)gr * K + k0 + col];
                *(uint4*)&Al[row][col] = v;
            }
        }
        // ---- stage BT tile (256 x 64) ----
#pragma unroll
        for (int it = 0; it < 8; ++it) {
            int idx = it * 256 + t;              // 0..2047 16B chunks
            int row = idx >> 3;
            int col = (idx & 7) * 8;
            uint4 v = *(const uint4*)&BT[(long)row * K + k0 + col];
            *(uint4*)&Bl[row][col] = v;
        }
        __syncthreads();

#pragma unroll
        for (int kt = 0; kt < 2; ++kt) {
            short8 af[4], bfr[4];
#pragma unroll
            for (int mt = 0; mt < 4; ++mt)
                af[mt] = *(const short8*)&Al[mt * 16 + r16][kt * 32 + q * 8];
#pragma unroll
            for (int nt = 0; nt < 4; ++nt)
                bfr[nt] = *(const short8*)&Bl[w * 64 + nt * 16 + r16][kt * 32 + q * 8];
#pragma unroll
            for (int mt = 0; mt < 4; ++mt)
#pragma unroll
                for (int nt = 0; nt < 4; ++nt)
                    acc[mt][nt] = __builtin_amdgcn_mfma_f32_16x16x32_bf16(
                        af[mt], bfr[nt], acc[mt][nt], 0, 0, 0);
        }
        __syncthreads();
    }

    // ---- epilogue: bias + SiLU + store ----
#pragma unroll
    for (int mt = 0; mt < 4; ++mt) {
#pragma unroll
        for (int rr = 0; rr < 4; ++rr) {
            int row = m0 + mt * 16 + q * 4 + rr;
            if (row < M) {
#pragma unroll
                for (int nt = 0; nt < 4; ++nt) {
                    int col = w * 64 + nt * 16 + r16;
                    float v = acc[mt][nt][rr];
                    if (BIAS) v += bias[col];
                    if (SILU) v = v / (1.f + __expf(-v));
                    if (OUT_F32)
                        ((float*)Cp)[(long)row * NOUT + col] = v;
                    else
                        ((__hip_bfloat16*)Cp)[(long)row * NOUT + col] = __float2bfloat16(v);
                }
            }
        }
    }
}

// ---------------------------------------------------------------------------
extern "C" void kernel_launch(void* const* d_in, const int* in_sizes, int n_in,
                              void* d_out, int out_size, void* d_ws, size_t ws_size,
                              hipStream_t stream)
{
    const float* x    = (const float*)d_in[0];
    const float* rbf  = (const float*)d_in[1];
    const int*   idx  = (const int*)d_in[2];
    const float* Wrbf = (const float*)d_in[3];
    const float* Wd   = (const float*)d_in[4];
    const float* Ws   = (const float*)d_in[5];
    const float* bs   = (const float*)d_in[6];

    int E = in_sizes[0] / HIDDEN;
    int M = out_size / NOUT;         // num_nodes

    char* ws = (char*)d_ws;
    float* hacc = (float*)ws;                                   // M*128 fp32
    size_t off = (size_t)M * HIDDEN * sizeof(float);
    __hip_bfloat16* actA = (__hip_bfloat16*)(ws + off); off += (size_t)M * NOUT * 2;
    __hip_bfloat16* actB = (__hip_bfloat16*)(ws + off); off += (size_t)M * NOUT * 2;
    __hip_bfloat16* WdT  = (__hip_bfloat16*)(ws + off); off += 256 * 128 * 2;
    __hip_bfloat16* WsT  = (__hip_bfloat16*)(ws + off); off += 3 * 256 * 256 * 2;

    hipMemsetAsync(hacc, 0, (size_t)M * HIDDEN * sizeof(float), stream);
    prep_weights<<<(256 * 128 + 3 * 256 * 256 + 255) / 256, 256, 0, stream>>>(Wd, Ws, WdT, WsT);
    gate_scatter<<<(E + 7) / 8, 256, 0, stream>>>(x, rbf, idx, Wrbf, hacc, E);

    int gblocks = (M + 63) / 64;
    gemm_k<128, true,  false, false, false><<<gblocks, 256, 0, stream>>>(hacc, WdT, nullptr, actA, M);
    gemm_k<256, false, true,  true,  false><<<gblocks, 256, 0, stream>>>(actA, WsT,             bs,       actB, M);
    gemm_k<256, false, true,  true,  false><<<gblocks, 256, 0, stream>>>(actB, WsT + 65536,     bs + 256, actA, M);
    gemm_k<256, false, true,  true,  true ><<<gblocks, 256, 0, stream>>>(actA, WsT + 2 * 65536, bs + 512, d_out, M);
}

// Round 2
// 720.657 us; speedup vs baseline: 1.9922x; 1.9922x over previous
//
#include <hip/hip_runtime.h>
#include <hip/hip_bf16.h>
#include <cstdint>

typedef __attribute__((ext_vector_type(8))) short short8;
typedef __attribute__((ext_vector_type(4))) float floatx4;

#define HIDDEN 128
#define NOUT 256

// ---------------------------------------------------------------------------
// Kernel 1: one-time weight convert + transpose to bf16.
// WdT[n][k] = W_down[k][n]   (256 x 128)
// WsT[l][n][k] = Ws[l][k][n] (3 x 256 x 256)
// ---------------------------------------------------------------------------
__global__ __launch_bounds__(256) void prep_weights(
    const float* __restrict__ Wd, const float* __restrict__ Ws,
    __hip_bfloat16* __restrict__ WdT, __hip_bfloat16* __restrict__ WsT)
{
    int tid = blockIdx.x * 256 + threadIdx.x;
    if (tid < 256 * 128) {
        int n = tid >> 7, k = tid & 127;
        WdT[tid] = __float2bfloat16(Wd[k * 256 + n]);
    }
    int tid2 = tid - 256 * 128;
    if (tid2 >= 0 && tid2 < 3 * 256 * 256) {
        int l = tid2 >> 16;
        int rem = tid2 & 65535;
        int n = rem >> 8, k = rem & 255;
        WsT[tid2] = __float2bfloat16(Ws[l * 65536 + k * 256 + n]);
    }
}

// ---------------------------------------------------------------------------
// CSR build: histogram -> exclusive scan -> stable fill.
// Replaces 76.8M device-scope fp32 atomics (memory-side RMW, 16B HBM
// write-through each -- measured 1.2GB WRITE_SIZE, 75G atomics/s cap)
// with 1.2M int atomics.
// ---------------------------------------------------------------------------
__global__ __launch_bounds__(256) void hist_k(
    const int* __restrict__ idx, int* __restrict__ cnt, int E)
{
    int e = blockIdx.x * 256 + threadIdx.x;
    if (e < E) atomicAdd(&cnt[idx[e]], 1);
}

__global__ __launch_bounds__(1024) void exscan_k(
    const int* __restrict__ cnt, int* __restrict__ offsets,
    int* __restrict__ cursor, int M)
{
    __shared__ int lds[1024];
    __shared__ int carry_s;
    int t = threadIdx.x;
    if (t == 0) carry_s = 0;
    __syncthreads();
    for (int base = 0; base < M; base += 1024) {
        int v = (base + t < M) ? cnt[base + t] : 0;
        lds[t] = v;
        __syncthreads();
        for (int s = 1; s < 1024; s <<= 1) {
            int a = (t >= s) ? lds[t - s] : 0;
            __syncthreads();
            lds[t] += a;
            __syncthreads();
        }
        int incl = lds[t];
        int c = carry_s;
        __syncthreads();                     // all reads of carry_s done
        if (t == 1023) carry_s = c + incl;   // chunk total (tail padded w/ 0)
        if (base + t < M) {
            int ex = c + incl - v;
            offsets[base + t] = ex;
            cursor[base + t] = ex;
        }
        __syncthreads();                     // carry_s visible next iter
    }
    if (t == 0) offsets[M] = carry_s;
}

__global__ __launch_bounds__(256) void fill_k(
    const int* __restrict__ idx, int* __restrict__ cursor,
    int* __restrict__ edge_ids, int E)
{
    int e = blockIdx.x * 256 + threadIdx.x;
    if (e < E) {
        int pos = atomicAdd(&cursor[idx[e]], 1);
        edge_ids[pos] = e;
    }
}

// ---------------------------------------------------------------------------
// Gather: one wave per node. Each lane owns 2 hidden channels (float2).
// Walks the node's CSR edge list, computes (rbf@W_rbf)*x on the fly,
// accumulates in fp32 registers, writes the hacc row exactly once.
// Edge id is wave-uniform -> readfirstlane so rbf loads scalarize.
// ---------------------------------------------------------------------------
__global__ __launch_bounds__(256) void gather_k(
    const float* __restrict__ x, const float* __restrict__ rbf,
    const float* __restrict__ Wrbf, const int* __restrict__ offsets,
    const int* __restrict__ edge_ids, float* __restrict__ hacc, int M)
{
    int t = threadIdx.x;
    int wave = t >> 6, lane = t & 63;
    int n = blockIdx.x * 4 + wave;
    if (n >= M) return;

    int c0 = lane * 2;
    float w0[6], w1[6];
#pragma unroll
    for (int r = 0; r < 6; ++r) {
        w0[r] = Wrbf[r * HIDDEN + c0];
        w1[r] = Wrbf[r * HIDDEN + c0 + 1];
    }

    int s = offsets[n], eend = offsets[n + 1];
    float a0 = 0.f, a1 = 0.f;
    for (int p = s; p < eend; ++p) {
        int e = __builtin_amdgcn_readfirstlane(edge_ids[p]);
        const float* rb = &rbf[(long)e * 6];
        float p0 = 0.f, p1 = 0.f;
#pragma unroll
        for (int r = 0; r < 6; ++r) {
            float rv = rb[r];
            p0 += rv * w0[r];
            p1 += rv * w1[r];
        }
        float2 xv = *(const float2*)&x[(long)e * HIDDEN + c0];
        a0 += p0 * xv.x;
        a1 += p1 * xv.y;
    }
    *(float2*)&hacc[(long)n * HIDDEN + c0] = make_float2(a0, a1);
}

// ---------------------------------------------------------------------------
// bf16 MFMA GEMM  C[M][256] = act(A[M][K] @ B[K][256] + bias)
// Block tile 64(M) x 256(N), BK=64, 4 waves; 16x16x32 bf16 MFMA.
// A[m=lane&15][k=(lane>>4)*8+j]; C/D: col=lane&15, row=(lane>>4)*4+reg.
// ---------------------------------------------------------------------------
template <int K, bool A_F32, bool BIAS, bool SILU, bool OUT_F32>
__global__ __launch_bounds__(256) void gemm_k(
    const void* __restrict__ Ap, const __hip_bfloat16* __restrict__ BT,
    const float* __restrict__ bias, void* __restrict__ Cp, int M)
{
    __shared__ __hip_bfloat16 Al[64][72];    // +8 pad
    __shared__ __hip_bfloat16 Bl[256][72];

    int t = threadIdx.x;
    int lane = t & 63, w = t >> 6;
    int q = lane >> 4, r16 = lane & 15;
    int m0 = blockIdx.x * 64;

    floatx4 acc[4][4] = {};

    for (int k0 = 0; k0 < K; k0 += 64) {
        if (A_F32) {
            const float* A = (const float*)Ap;
#pragma unroll
            for (int it = 0; it < 4; ++it) {
                int idx = it * 256 + t;
                int row = idx >> 4;
                int col = (idx & 15) * 4;
                int gr = m0 + row; if (gr >= M) gr = M - 1;
                float4 v = *(const float4*)&A[(long)gr * K + k0 + col];
                Al[row][col + 0] = __float2bfloat16(v.x);
                Al[row][col + 1] = __float2bfloat16(v.y);
                Al[row][col + 2] = __float2bfloat16(v.z);
                Al[row][col + 3] = __float2bfloat16(v.w);
            }
        } else {
            const __hip_bfloat16* A = (const __hip_bfloat16*)Ap;
#pragma unroll
            for (int it = 0; it < 2; ++it) {
                int idx = it * 256 + t;
                int row = idx >> 3;
                int col = (idx & 7) * 8;
                int gr = m0 + row; if (gr >= M) gr = M - 1;
                uint4 v = *(const uint4*)&A[(long)gr * K + k0 + col];
                *(uint4*)&Al[row][col] = v;
            }
        }
#pragma unroll
        for (int it = 0; it < 8; ++it) {
            int idx = it * 256 + t;
            int row = idx >> 3;
            int col = (idx & 7) * 8;
            uint4 v = *(const uint4*)&BT[(long)row * K + k0 + col];
            *(uint4*)&Bl[row][col] = v;
        }
        __syncthreads();

#pragma unroll
        for (int kt = 0; kt < 2; ++kt) {
            short8 af[4], bfr[4];
#pragma unroll
            for (int mt = 0; mt < 4; ++mt)
                af[mt] = *(const short8*)&Al[mt * 16 + r16][kt * 32 + q * 8];
#pragma unroll
            for (int nt = 0; nt < 4; ++nt)
                bfr[nt] = *(const short8*)&Bl[w * 64 + nt * 16 + r16][kt * 32 + q * 8];
#pragma unroll
            for (int mt = 0; mt < 4; ++mt)
#pragma unroll
                for (int nt = 0; nt < 4; ++nt)
                    acc[mt][nt] = __builtin_amdgcn_mfma_f32_16x16x32_bf16(
                        af[mt], bfr[nt], acc[mt][nt], 0, 0, 0);
        }
        __syncthreads();
    }

#pragma unroll
    for (int mt = 0; mt < 4; ++mt) {
#pragma unroll
        for (int rr = 0; rr < 4; ++rr) {
            int row = m0 + mt * 16 + q * 4 + rr;
            if (row < M) {
#pragma unroll
                for (int nt = 0; nt < 4; ++nt) {
                    int col = w * 64 + nt * 16 + r16;
                    float v = acc[mt][nt][rr];
                    if (BIAS) v += bias[col];
                    if (SILU) v = v / (1.f + __expf(-v));
                    if (OUT_F32)
                        ((float*)Cp)[(long)row * NOUT + col] = v;
                    else
                        ((__hip_bfloat16*)Cp)[(long)row * NOUT + col] = __float2bfloat16(v);
                }
            }
        }
    }
}

// ---------------------------------------------------------------------------
extern "C" void kernel_launch(void* const* d_in, const int* in_sizes, int n_in,
                              void* d_out, int out_size, void* d_ws, size_t ws_size,
                              hipStream_t stream)
{
    const float* x    = (const float*)d_in[0];
    const float* rbf  = (const float*)d_in[1];
    const int*   idx  = (const int*)d_in[2];
    const float* Wrbf = (const float*)d_in[3];
    const float* Wd   = (const float*)d_in[4];
    const float* Ws   = (const float*)d_in[5];
    const float* bs   = (const float*)d_in[6];

    int E = in_sizes[0] / HIDDEN;
    int M = out_size / NOUT;         // num_nodes

    char* ws = (char*)d_ws;
    float* hacc = (float*)ws;                                   // M*128 fp32
    size_t off = (size_t)M * HIDDEN * sizeof(float);
    __hip_bfloat16* actA = (__hip_bfloat16*)(ws + off); off += (size_t)M * NOUT * 2;
    __hip_bfloat16* actB = (__hip_bfloat16*)(ws + off); off += (size_t)M * NOUT * 2;
    __hip_bfloat16* WdT  = (__hip_bfloat16*)(ws + off); off += 256 * 128 * 2;
    __hip_bfloat16* WsT  = (__hip_bfloat16*)(ws + off); off += 3 * 256 * 256 * 2;

    // CSR scratch aliased into the actB region: actB is first written by
    // GEMM layer 1 (output of layer-0 MLP), and all CSR use (hist..gather)
    // completes before that on the same stream.
    char* csr = (char*)actB;
    int* cnt      = (int*)csr;                   csr += (size_t)M * 4;
    int* offsets  = (int*)csr;                   csr += (size_t)(M + 1) * 4;
    int* cursor   = (int*)csr;                   csr += (size_t)M * 4;
    int* edge_ids = (int*)csr;

    hipMemsetAsync(cnt, 0, (size_t)M * sizeof(int), stream);
    prep_weights<<<(256 * 128 + 3 * 256 * 256 + 255) / 256, 256, 0, stream>>>(Wd, Ws, WdT, WsT);
    hist_k<<<(E + 255) / 256, 256, 0, stream>>>(idx, cnt, E);
    exscan_k<<<1, 1024, 0, stream>>>(cnt, offsets, cursor, M);
    fill_k<<<(E + 255) / 256, 256, 0, stream>>>(idx, cursor, edge_ids, E);
    gather_k<<<(M + 3) / 4, 256, 0, stream>>>(x, rbf, Wrbf, offsets, edge_ids, hacc, M);

    int gblocks = (M + 63) / 64;
    gemm_k<128, true,  false, false, false><<<gblocks, 256, 0, stream>>>(hacc, WdT, nullptr, actA, M);
    gemm_k<256, false, true,  true,  false><<<gblocks, 256, 0, stream>>>(actA, WsT,             bs,       actB, M);
    gemm_k<256, false, true,  true,  false><<<gblocks, 256, 0, stream>>>(actB, WsT + 65536,     bs + 256, actA, M);
    gemm_k<256, false, true,  true,  true ><<<gblocks, 256, 0, stream>>>(actA, WsT + 2 * 65536, bs + 512, d_out, M);
}

// Round 3
// 709.704 us; speedup vs baseline: 2.0230x; 1.0154x over previous
//
#include <hip/hip_runtime.h>
#include <hip/hip_bf16.h>
#include <cstdint>

typedef __attribute__((ext_vector_type(8))) short short8;
typedef __attribute__((ext_vector_type(4))) float floatx4;

#define HIDDEN 128
#define NOUT 256

// ---------------------------------------------------------------------------
// One-time weight convert + transpose to bf16.
// WdT[n][k] = W_down[k][n] (256x128); WsT[l][n][k] = Ws[l][k][n] (3x256x256)
// ---------------------------------------------------------------------------
__global__ __launch_bounds__(256) void prep_weights(
    const float* __restrict__ Wd, const float* __restrict__ Ws,
    __hip_bfloat16* __restrict__ WdT, __hip_bfloat16* __restrict__ WsT)
{
    int tid = blockIdx.x * 256 + threadIdx.x;
    if (tid < 256 * 128) {
        int n = tid >> 7, k = tid & 127;
        WdT[tid] = __float2bfloat16(Wd[k * 256 + n]);
    }
    int tid2 = tid - 256 * 128;
    if (tid2 >= 0 && tid2 < 3 * 256 * 256) {
        int l = tid2 >> 16;
        int rem = tid2 & 65535;
        int n = rem >> 8, k = rem & 255;
        WsT[tid2] = __float2bfloat16(Ws[l * 65536 + k * 256 + n]);
    }
}

// ---------------------------------------------------------------------------
// CSR build: histogram -> 3-kernel parallel exclusive scan -> stable fill.
// (Round-2's single-workgroup Hillis-Steele scan was ~O(1000) barriers on
//  one CU; replaced with chunk-reduce / wave-scan / chunk-fill.)
// ---------------------------------------------------------------------------
__global__ __launch_bounds__(256) void hist_k(
    const int* __restrict__ idx, int* __restrict__ cnt, int E)
{
    int e = blockIdx.x * 256 + threadIdx.x;
    if (e < E) atomicAdd(&cnt[idx[e]], 1);
}

// per-1024-chunk sums
__global__ __launch_bounds__(256) void scan_blocksum_k(
    const int* __restrict__ cnt, int* __restrict__ blocksum, int M)
{
    int base = blockIdx.x * 1024;
    int t = threadIdx.x;
    int s = 0;
#pragma unroll
    for (int j = 0; j < 4; ++j) {
        int p = base + t * 4 + j;
        if (p < M) s += cnt[p];
    }
#pragma unroll
    for (int d = 32; d > 0; d >>= 1) s += __shfl_down(s, d);
    __shared__ int wsum[4];
    if ((t & 63) == 0) wsum[t >> 6] = s;
    __syncthreads();
    if (t == 0) blocksum[blockIdx.x] = wsum[0] + wsum[1] + wsum[2] + wsum[3];
}

// single-wave exclusive scan of the (<=~64) chunk sums; also writes offsets[M]
__global__ __launch_bounds__(64) void scan_base_k(
    const int* __restrict__ blocksum, int* __restrict__ blockbase,
    int* __restrict__ offsets, int nb, int M)
{
    int lane = threadIdx.x;
    int carry = 0;
    for (int base = 0; base < nb; base += 64) {
        int v = (base + lane < nb) ? blocksum[base + lane] : 0;
        int incl = v;
#pragma unroll
        for (int d = 1; d < 64; d <<= 1) {
            int u = __shfl_up(incl, d);
            if (lane >= d) incl += u;
        }
        if (base + lane < nb) blockbase[base + lane] = carry + incl - v;
        carry += __shfl(incl, 63);
    }
    if (lane == 0) offsets[M] = carry;
}

// per-chunk offset fill: thread-local 4-seq + wave shfl scan + cross-wave LDS
__global__ __launch_bounds__(256) void scan_offsets_k(
    const int* __restrict__ cnt, const int* __restrict__ blockbase,
    int* __restrict__ offsets, int* __restrict__ cursor, int M)
{
    int base = blockIdx.x * 1024;
    int t = threadIdx.x, lane = t & 63, wv = t >> 6;
    int v[4];
    int s = 0;
#pragma unroll
    for (int j = 0; j < 4; ++j) {
        int p = base + t * 4 + j;
        v[j] = (p < M) ? cnt[p] : 0;
        s += v[j];
    }
    int incl = s;
#pragma unroll
    for (int d = 1; d < 64; d <<= 1) {
        int u = __shfl_up(incl, d);
        if (lane >= d) incl += u;
    }
    __shared__ int wtot[4];
    if (lane == 63) wtot[wv] = incl;
    __syncthreads();
    int wbase = 0;
    for (int j = 0; j < wv; ++j) wbase += wtot[j];
    int start = blockbase[blockIdx.x] + wbase + incl - s;
#pragma unroll
    for (int j = 0; j < 4; ++j) {
        int p = base + t * 4 + j;
        if (p < M) { offsets[p] = start; cursor[p] = start; }
        start += v[j];
    }
}

__global__ __launch_bounds__(256) void fill_k(
    const int* __restrict__ idx, int* __restrict__ cursor,
    int* __restrict__ edge_ids, int E)
{
    int e = blockIdx.x * 256 + threadIdx.x;
    if (e < E) {
        int pos = atomicAdd(&cursor[idx[e]], 1);
        edge_ids[pos] = e;
    }
}

// ---------------------------------------------------------------------------
// Gather: one wave per node, lane owns 2 hidden channels. Walks the CSR edge
// list, computes (rbf@W_rbf)*x on the fly, accumulates fp32 in registers,
// writes the hacc row exactly once (no fp32 atomics).
// ---------------------------------------------------------------------------
__global__ __launch_bounds__(256) void gather_k(
    const float* __restrict__ x, const float* __restrict__ rbf,
    const float* __restrict__ Wrbf, const int* __restrict__ offsets,
    const int* __restrict__ edge_ids, float* __restrict__ hacc, int M)
{
    int t = threadIdx.x;
    int wave = t >> 6, lane = t & 63;
    int n = blockIdx.x * 4 + wave;
    if (n >= M) return;

    int c0 = lane * 2;
    float w0[6], w1[6];
#pragma unroll
    for (int r = 0; r < 6; ++r) {
        w0[r] = Wrbf[r * HIDDEN + c0];
        w1[r] = Wrbf[r * HIDDEN + c0 + 1];
    }

    int s = offsets[n], eend = offsets[n + 1];
    float a0 = 0.f, a1 = 0.f;
    for (int p = s; p < eend; ++p) {
        int e = __builtin_amdgcn_readfirstlane(edge_ids[p]);
        const float* rb = &rbf[(long)e * 6];
        float p0 = 0.f, p1 = 0.f;
#pragma unroll
        for (int r = 0; r < 6; ++r) {
            float rv = rb[r];
            p0 += rv * w0[r];
            p1 += rv * w1[r];
        }
        float2 xv = *(const float2*)&x[(long)e * HIDDEN + c0];
        a0 += p0 * xv.x;
        a1 += p1 * xv.y;
    }
    *(float2*)&hacc[(long)n * HIDDEN + c0] = make_float2(a0, a1);
}

// ---------------------------------------------------------------------------
// Fused MLP: down-proj + 3 SiLU layers in ONE kernel. Block = 64 rows,
// resident in LDS across all layers (no activation round-trips to global).
// Per layer: stage 64-wide K-slab of B^T into LDS -> 16x16x32 bf16 MFMA ->
// epilogue writes activations back into the A-buffer (C/D layout -> A layout).
// LDS: Al 64x264 bf16 (33.8KB) + Wl 256x72 (36.9KB) = 70.6KB -> 2 blocks/CU.
// Layouts (HW-verified): A[m=lane&15][k=(lane>>4)*8+j];
//                        C/D col=lane&15, row=(lane>>4)*4+reg.
// ---------------------------------------------------------------------------
__global__ __launch_bounds__(256) void mlp_fused(
    const float* __restrict__ hacc, const __hip_bfloat16* __restrict__ WdT,
    const __hip_bfloat16* __restrict__ WsT, const float* __restrict__ bs,
    float* __restrict__ out, int M)
{
    __shared__ __hip_bfloat16 Al[64][264];   // +8 pad
    __shared__ __hip_bfloat16 Wl[256][72];   // +8 pad

    int t = threadIdx.x;
    int lane = t & 63, w = t >> 6;
    int q = lane >> 4, r16 = lane & 15;
    int m0 = blockIdx.x * 64;

    // stage hacc tile (64 x 128 fp32) -> Al bf16
#pragma unroll
    for (int it = 0; it < 8; ++it) {
        int idx = it * 256 + t;          // 2048 float4 chunks
        int row = idx >> 5;              // 32 chunks / row
        int col = (idx & 31) * 4;
        int gr = m0 + row; if (gr >= M) gr = M - 1;
        float4 v = *(const float4*)&hacc[(long)gr * HIDDEN + col];
        Al[row][col + 0] = __float2bfloat16(v.x);
        Al[row][col + 1] = __float2bfloat16(v.y);
        Al[row][col + 2] = __float2bfloat16(v.z);
        Al[row][col + 3] = __float2bfloat16(v.w);
    }
    __syncthreads();

    for (int layer = 0; layer < 4; ++layer) {
        const int K = (layer == 0) ? 128 : 256;
        const __hip_bfloat16* BT = (layer == 0) ? WdT : WsT + (layer - 1) * 65536;
        floatx4 acc[4][4] = {};

        for (int k0 = 0; k0 < K; k0 += 64) {
            // stage weight slab: 256 n-rows x 64 k
#pragma unroll
            for (int it = 0; it < 8; ++it) {
                int idx = it * 256 + t;
                int row = idx >> 3;
                int col = (idx & 7) * 8;
                *(uint4*)&Wl[row][col] = *(const uint4*)&BT[(long)row * K + k0 + col];
            }
            __syncthreads();
#pragma unroll
            for (int kt = 0; kt < 2; ++kt) {
                short8 af[4], bfr[4];
#pragma unroll
                for (int mt = 0; mt < 4; ++mt)
                    af[mt] = *(const short8*)&Al[mt * 16 + r16][k0 + kt * 32 + q * 8];
#pragma unroll
                for (int nt = 0; nt < 4; ++nt)
                    bfr[nt] = *(const short8*)&Wl[w * 64 + nt * 16 + r16][kt * 32 + q * 8];
#pragma unroll
                for (int mt = 0; mt < 4; ++mt)
#pragma unroll
                    for (int nt = 0; nt < 4; ++nt)
                        acc[mt][nt] = __builtin_amdgcn_mfma_f32_16x16x32_bf16(
                            af[mt], bfr[nt], acc[mt][nt], 0, 0, 0);
            }
            __syncthreads();   // Wl reuse next slab; also fences Al reads on last slab
        }

        if (layer < 3) {
            // epilogue -> back into Al (bias+SiLU except after down-proj)
            const float* bias = (layer == 0) ? nullptr : bs + (layer - 1) * 256;
#pragma unroll
            for (int mt = 0; mt < 4; ++mt) {
#pragma unroll
                for (int rr = 0; rr < 4; ++rr) {
                    int row = mt * 16 + q * 4 + rr;
#pragma unroll
                    for (int nt = 0; nt < 4; ++nt) {
                        int col = w * 64 + nt * 16 + r16;
                        float v = acc[mt][nt][rr];
                        if (layer > 0) { v += bias[col]; v = v / (1.f + __expf(-v)); }
                        Al[row][col] = __float2bfloat16(v);
                    }
                }
            }
            __syncthreads();
        } else {
            const float* bias = bs + 2 * 256;
#pragma unroll
            for (int mt = 0; mt < 4; ++mt) {
#pragma unroll
                for (int rr = 0; rr < 4; ++rr) {
                    int row = m0 + mt * 16 + q * 4 + rr;
                    if (row < M) {
#pragma unroll
                        for (int nt = 0; nt < 4; ++nt) {
                            int col = w * 64 + nt * 16 + r16;
                            float v = acc[mt][nt][rr] + bias[col];
                            v = v / (1.f + __expf(-v));
                            out[(long)row * NOUT + col] = v;
                        }
                    }
                }
            }
        }
    }
}

// ---------------------------------------------------------------------------
extern "C" void kernel_launch(void* const* d_in, const int* in_sizes, int n_in,
                              void* d_out, int out_size, void* d_ws, size_t ws_size,
                              hipStream_t stream)
{
    const float* x    = (const float*)d_in[0];
    const float* rbf  = (const float*)d_in[1];
    const int*   idx  = (const int*)d_in[2];
    const float* Wrbf = (const float*)d_in[3];
    const float* Wd   = (const float*)d_in[4];
    const float* Ws   = (const float*)d_in[5];
    const float* bs   = (const float*)d_in[6];

    int E = in_sizes[0] / HIDDEN;
    int M = out_size / NOUT;         // num_nodes
    int nb = (M + 1023) / 1024;

    char* ws = (char*)d_ws;
    float* hacc = (float*)ws;                                    // M*128 fp32
    size_t off = (size_t)M * HIDDEN * sizeof(float);
    __hip_bfloat16* WdT = (__hip_bfloat16*)(ws + off); off += 256 * 128 * 2;
    __hip_bfloat16* WsT = (__hip_bfloat16*)(ws + off); off += 3 * 256 * 256 * 2;
    int* cnt       = (int*)(ws + off); off += (size_t)M * 4;
    int* offsets   = (int*)(ws + off); off += (size_t)(M + 1) * 4;
    int* cursor    = (int*)(ws + off); off += (size_t)M * 4;
    int* edge_ids  = (int*)(ws + off); off += (size_t)E * 4;
    int* blocksum  = (int*)(ws + off); off += (size_t)nb * 4;
    int* blockbase = (int*)(ws + off); off += (size_t)nb * 4;

    hipMemsetAsync(cnt, 0, (size_t)M * sizeof(int), stream);
    prep_weights<<<(256 * 128 + 3 * 256 * 256 + 255) / 256, 256, 0, stream>>>(Wd, Ws, WdT, WsT);
    hist_k<<<(E + 255) / 256, 256, 0, stream>>>(idx, cnt, E);
    scan_blocksum_k<<<nb, 256, 0, stream>>>(cnt, blocksum, M);
    scan_base_k<<<1, 64, 0, stream>>>(blocksum, blockbase, offsets, nb, M);
    scan_offsets_k<<<nb, 256, 0, stream>>>(cnt, blockbase, offsets, cursor, M);
    fill_k<<<(E + 255) / 256, 256, 0, stream>>>(idx, cursor, edge_ids, E);
    gather_k<<<(M + 3) / 4, 256, 0, stream>>>(x, rbf, Wrbf, offsets, edge_ids, hacc, M);
    mlp_fused<<<(M + 63) / 64, 256, 0, stream>>>(hacc, WdT, WsT, bs, (float*)d_out, M);
}